// Round 3
// baseline (451.124 us; speedup 1.0000x reference)
//
#include <hip/hip_runtime.h>

#define NTOK 4096          // B*N
#define TPB_TOK 4          // tokens per block (software pipeline depth)
#define GRID (NTOK / TPB_TOK)
#define AST  264           // LDS A-tile row stride in shorts (bank-conflict pad)

using short8  = __attribute__((ext_vector_type(8))) short;
using short4v = __attribute__((ext_vector_type(4))) short;
using floatx4 = __attribute__((ext_vector_type(4))) float;

static __device__ __forceinline__ short f2bf(float f) {
  union { float f; unsigned u; } v; v.f = f;
  unsigned u = v.u;
  u = (u + 0x7fffu + ((u >> 16) & 1u)) >> 16;   // RNE truncate to bf16
  return (short)u;
}

static __device__ __forceinline__ float bf2f(short s) {
  union { unsigned u; float f; } v; v.u = ((unsigned)(unsigned short)s) << 16;
  return v.f;
}

// Branchless GELU: erf via Abramowitz-Stegun 7.1.26 (|eps|<=1.5e-7), ~15 VALU.
static __device__ __forceinline__ float fast_gelu(float z) {
  float x  = z * 0.70710678118654752f;
  float ax = fabsf(x);
  float t  = __builtin_amdgcn_rcpf(fmaf(0.3275911f, ax, 1.0f));
  float em = __expf(-ax * ax);
  float p  = fmaf(fmaf(fmaf(fmaf(1.061405429f, t, -1.453152027f), t,
                            1.421413741f), t, -0.284496736f), t, 0.254829592f);
  float er = fmaf(-p * t, em, 1.0f);                 // erf(|x|) in [0,1)
  unsigned sgn = __float_as_uint(x) & 0x80000000u;
  er = __uint_as_float(__float_as_uint(er) | sgn);   // copysign
  return z * fmaf(0.5f, er, 0.5f);
}

// Coalesced pre-swizzle of W1[0:256,0:256] into bf16 B-fragment order.
__global__ void prep_w1(const float* __restrict__ W1, short* __restrict__ W1s) {
  const int n  = threadIdx.x;     // 0..255
  const int kb = blockIdx.x;      // 0..31
  const int s  = kb >> 2;
  const int l  = ((kb & 3) << 4) | (n & 15);
  const int t  = n >> 4;
  short8 o;
  #pragma unroll
  for (int j = 0; j < 8; ++j)
    o[j] = f2bf(W1[(kb * 8 + j) * 256 + n]);
  *(short8*)(W1s + (((s * 16 + t) * 64 + l) << 3)) = o;
}

__global__ void __launch_bounds__(256) agg_kernel(
    const float* __restrict__ sampled, const float* __restrict__ valid,
    const float* __restrict__ y_norm, const float* __restrict__ W1,
    const float* __restrict__ b1, const float* __restrict__ W2,
    const float* __restrict__ b2, const short* __restrict__ W1s,
    float* __restrict__ out) {
  __shared__ __align__(16) short Abf[64 * AST];   // 33,792 B bf16 A tile
  __shared__ float wlog[4][64];                   // per-wave partial logits
  __shared__ float ynl[64];                       // y_norm

  const int tid = threadIdx.x;
  const int wv  = tid >> 6;        // wave 0..3 -> owns n in [64*wv, 64*wv+64)
  const int ln  = tid & 63;
  const int q   = ln >> 4;
  const int c15 = ln & 15;

  if (tid < 64) ynl[tid] = y_norm[tid];

  // per-thread weight constants — invariant across tokens, hoisted
  float w2v[4], b1v[4], wlv[4];
  #pragma unroll
  for (int nt = 0; nt < 4; ++nt) {
    int n = wv * 64 + nt * 16 + c15;
    w2v[nt] = W2[n];
    b1v[nt] = b1[n];
    wlv[nt] = W1[65536 + n];        // W1[256][n] — the y-feature row
  }
  const float b2s = b2[0];

  const int tok0 = blockIdx.x * TPB_TOK;

  // ---- prefetch token 0 tile + valid into registers ----
  float4 v0[8], v1[8];
  float vvn;
  {
    const float4* S4 = (const float4*)(sampled + ((size_t)tok0 << 14));
    #pragma unroll
    for (int it = 0; it < 8; ++it) v0[it] = S4[it * 256 + tid];
    #pragma unroll
    for (int it = 0; it < 8; ++it) v1[it] = S4[(8 + it) * 256 + tid];
    vvn = valid[tok0 * 64 + ln];
  }

  for (int t = 0; t < TPB_TOK; ++t) {
    const int tok = tok0 + t;
    const float4* Sn = (const float4*)(sampled + ((size_t)(tok + 1) << 14));

    __syncthreads();   // previous token's phase-4 reads of Abf are done

    // ---- phase 0: convert prefetched regs -> LDS bf16 tile ----
    #pragma unroll
    for (int it = 0; it < 8; ++it) {
      int y = it * 4 + wv;
      short4v p;
      p[0] = f2bf(v0[it].x); p[1] = f2bf(v0[it].y);
      p[2] = f2bf(v0[it].z); p[3] = f2bf(v0[it].w);
      *(short4v*)(&Abf[y * AST + (ln << 2)]) = p;
    }
    #pragma unroll
    for (int it = 0; it < 8; ++it) {
      int y = (8 + it) * 4 + wv;
      short4v p;
      p[0] = f2bf(v1[it].x); p[1] = f2bf(v1[it].y);
      p[2] = f2bf(v1[it].z); p[3] = f2bf(v1[it].w);
      *(short4v*)(&Abf[y * AST + (ln << 2)]) = p;
    }
    const float vv = vvn;
    __syncthreads();

    // ---- prefetch next token, first half (overlaps GEMM) ----
    if (t + 1 < TPB_TOK) {
      #pragma unroll
      for (int it = 0; it < 8; ++it) v0[it] = Sn[it * 256 + tid];
      vvn = valid[(tok + 1) * 64 + ln];
    }

    // ---- phase 1: GEMM  z[64x256] = A(bf16) * W1[0:256](bf16), fp32 acc ----
    const floatx4 fzero = {0.f, 0.f, 0.f, 0.f};
    floatx4 acc[4][4];
    #pragma unroll
    for (int mt = 0; mt < 4; ++mt)
      #pragma unroll
      for (int nt = 0; nt < 4; ++nt) acc[mt][nt] = fzero;

    #pragma unroll
    for (int s = 0; s < 8; ++s) {
      short8 af[4];
      #pragma unroll
      for (int mt = 0; mt < 4; ++mt)
        af[mt] = *(const short8*)(&Abf[(mt * 16 + c15) * AST + s * 32 + q * 8]);
      #pragma unroll
      for (int nt = 0; nt < 4; ++nt) {
        const int tt = wv * 4 + nt;
        short8 bfrag = *(const short8*)(W1s + (((s * 16 + tt) * 64 + ln) << 3));
        #pragma unroll
        for (int mt = 0; mt < 4; ++mt)
          acc[mt][nt] = __builtin_amdgcn_mfma_f32_16x16x32_bf16(af[mt], bfrag, acc[mt][nt], 0, 0, 0);
      }
    }

    // ---- prefetch next token, second half (overlaps epilogue) ----
    if (t + 1 < TPB_TOK) {
      #pragma unroll
      for (int it = 0; it < 8; ++it) v1[it] = Sn[(8 + it) * 256 + tid];
    }

    // ---- phase 2: h = gelu(z + y*W1_last + b1); partial logits = h.W2 ----
    #pragma unroll
    for (int mt = 0; mt < 4; ++mt) {
      #pragma unroll
      for (int r = 0; r < 4; ++r) {
        int m = mt * 16 + q * 4 + r;    // D row = quad*4 + reg
        float ym = ynl[m];
        float p = 0.f;
        #pragma unroll
        for (int nt = 0; nt < 4; ++nt) {
          float z = acc[mt][nt][r] + ym * wlv[nt] + b1v[nt];
          p += fast_gelu(z) * w2v[nt];
        }
        p += __shfl_xor(p, 1);
        p += __shfl_xor(p, 2);
        p += __shfl_xor(p, 4);
        p += __shfl_xor(p, 8);
        if (c15 == 0) wlog[wv][m] = p;
      }
    }
    __syncthreads();

    // ---- phase 3: masked softmax over Y=64, redundantly in every wave ----
    float lg = wlog[0][ln] + wlog[1][ln] + wlog[2][ln] + wlog[3][ln] + b2s;
    float lm = (vv < 0.5f) ? -10000.0f : lg;
    float mx = lm;
    #pragma unroll
    for (int d = 32; d > 0; d >>= 1) mx = fmaxf(mx, __shfl_xor(mx, d));
    float e   = __expf(lm - mx) * vv;   // e*valid
    float s2  = e;
    #pragma unroll
    for (int d = 32; d > 0; d >>= 1) s2 += __shfl_xor(s2, d);
    // softmax(l)*v renormalized by its own sum == e*v / sum(e*v) for binary v
    float wgt = e / fmaxf(s2, 1e-6f);   // lane ln holds weight for y=ln

    // ---- phase 4: out[c] = sum_y A_bf16[y][c] * w[y]  (LDS, no barrier) ----
    float a0 = 0.f;
    #pragma unroll
    for (int y = 0; y < 64; ++y) {
      float wy = __shfl(wgt, y);        // compile-time lane -> readlane
      a0 = fmaf(bf2f(Abf[y * AST + tid]), wy, a0);
    }
    out[(size_t)tok * 256 + tid] = a0;
  }
}

extern "C" void kernel_launch(void* const* d_in, const int* in_sizes, int n_in,
                              void* d_out, int out_size, void* d_ws, size_t ws_size,
                              hipStream_t stream) {
  const float* sampled = (const float*)d_in[0];
  const float* valid   = (const float*)d_in[1];
  const float* y_norm  = (const float*)d_in[2];
  const float* W1      = (const float*)d_in[3];   // [257,256]
  const float* b1      = (const float*)d_in[4];
  const float* W2      = (const float*)d_in[5];
  const float* b2      = (const float*)d_in[6];
  short* W1s = (short*)d_ws;                      // 128 KiB swizzled bf16 W1
  float* out = (float*)d_out;

  prep_w1<<<32, 256, 0, stream>>>(W1, W1s);
  agg_kernel<<<GRID, 256, 0, stream>>>(sampled, valid, y_norm, W1, b1, W2, b2, W1s, out);
}

// Round 4
// 418.052 us; speedup vs baseline: 1.0791x; 1.0791x over previous
//
#include <hip/hip_runtime.h>
#include <hip/hip_bf16.h>

#define NTOK 4096          // B*N
#define AST  264           // LDS A-tile row stride in shorts (bank-conflict pad)

using short8  = __attribute__((ext_vector_type(8))) short;
using floatx4 = __attribute__((ext_vector_type(4))) float;

static __device__ __forceinline__ short f2bf(float f) {
  union { float f; unsigned u; } v; v.f = f;
  unsigned u = v.u;
  u = (u + 0x7fffu + ((u >> 16) & 1u)) >> 16;   // RNE truncate to bf16
  return (short)u;
}

static __device__ __forceinline__ float bf2f(short s) {
  union { unsigned u; float f; } v; v.u = ((unsigned)(unsigned short)s) << 16;
  return v.f;
}

// pack two floats to bf16x2 (RNE), low half = a
static __device__ __forceinline__ unsigned pack_bf2(float a, float b) {
  __hip_bfloat162 h = __float22bfloat162_rn(float2{a, b});
  union { __hip_bfloat162 h; unsigned u; } v; v.h = h;
  return v.u;
}

// Branchless GELU: erf via Abramowitz-Stegun 7.1.26 (|eps|<=1.5e-7), ~15 VALU.
static __device__ __forceinline__ float fast_gelu(float z) {
  float x  = z * 0.70710678118654752f;
  float ax = fabsf(x);
  float t  = __builtin_amdgcn_rcpf(fmaf(0.3275911f, ax, 1.0f));
  float em = __expf(-ax * ax);
  float p  = fmaf(fmaf(fmaf(fmaf(1.061405429f, t, -1.453152027f), t,
                            1.421413741f), t, -0.284496736f), t, 0.254829592f);
  float er = fmaf(-p * t, em, 1.0f);                 // erf(|x|) in [0,1)
  unsigned sgn = __float_as_uint(x) & 0x80000000u;
  er = __uint_as_float(__float_as_uint(er) | sgn);   // copysign
  return z * fmaf(0.5f, er, 0.5f);
}

// Coalesced pre-swizzle of W1[0:256,0:256] into bf16 B-fragment order:
// W1s[((s*16 + t)*64 + l)*8 + j] = bf16(W1[k*256 + n]),
//   k = s*32 + (l>>4)*8 + j, n = t*16 + (l&15).
__global__ void prep_w1(const float* __restrict__ W1, short* __restrict__ W1s) {
  const int n  = threadIdx.x;     // 0..255
  const int kb = blockIdx.x;      // 0..31
  const int s  = kb >> 2;
  const int l  = ((kb & 3) << 4) | (n & 15);
  const int t  = n >> 4;
  short8 o;
  #pragma unroll
  for (int j = 0; j < 8; ++j)
    o[j] = f2bf(W1[(kb * 8 + j) * 256 + n]);
  *(short8*)(W1s + (((s * 16 + t) * 64 + l) << 3)) = o;
}

// 512 threads = 8 waves; wave wv owns n-tiles tt = {2wv, 2wv+1} (16 cols each).
// 2 blocks/CU resident (LDS ~34KB, VGPR<=128 via launch_bounds(512,4)).
__global__ void __launch_bounds__(512, 4) agg_kernel(
    const float* __restrict__ sampled, const float* __restrict__ valid,
    const float* __restrict__ y_norm, const float* __restrict__ W1,
    const float* __restrict__ b1, const float* __restrict__ W2,
    const float* __restrict__ b2, const short* __restrict__ W1s,
    float* __restrict__ out) {
  __shared__ __align__(16) short Abf[64 * AST];   // 33,792 B bf16 A tile
  __shared__ float wlog[8][64];                   // per-wave partial logits
  __shared__ float ynl[64];                       // y_norm

  const int tid = threadIdx.x;
  const int wv  = tid >> 6;        // 0..7
  const int ln  = tid & 63;
  const int q   = ln >> 4;
  const int c15 = ln & 15;
  const int tok = blockIdx.x;

  const float* S = sampled + ((size_t)tok << 14);   // 64*256 floats
  if (tid < 64) ynl[tid] = y_norm[tid];
  const float vv = valid[tok * 64 + ln];            // prefetch early

  // per-thread weight constants (nt in {0,1})
  float w2v[2], b1v[2], wlv[2];
  #pragma unroll
  for (int nt = 0; nt < 2; ++nt) {
    int n = (wv * 2 + nt) * 16 + c15;
    w2v[nt] = W2[n];
    b1v[nt] = b1[n];
    wlv[nt] = W1[65536 + n];        // y-feature row W1[256][n]
  }
  const float b2s = b2[0];

  // ---- phase 0: stage 64KB tile -> LDS bf16 (8 float4/thread) ----
  {
    const float4* S4 = (const float4*)S;
    float4 v[8];
    #pragma unroll
    for (int it = 0; it < 8; ++it) v[it] = S4[it * 512 + tid];
    #pragma unroll
    for (int it = 0; it < 8; ++it) {
      int j  = it * 512 + tid;
      int y  = j >> 6;
      int k4 = (j & 63) << 2;       // float index within row
      uint2 p;
      p.x = pack_bf2(v[it].x, v[it].y);
      p.y = pack_bf2(v[it].z, v[it].w);
      *(uint2*)(&Abf[y * AST + k4]) = p;
    }
  }
  __syncthreads();

  // ---- phase 1: GEMM with b-frag register double-buffer ----
  const short8* Wq = (const short8*)W1s;
  const int tb = wv * 2;           // first n-tile of this wave

  const floatx4 fzero = {0.f, 0.f, 0.f, 0.f};
  floatx4 acc[4][2];
  #pragma unroll
  for (int mt = 0; mt < 4; ++mt) { acc[mt][0] = fzero; acc[mt][1] = fzero; }

  short8 bc0 = Wq[(0 * 16 + tb + 0) * 64 + ln];
  short8 bc1 = Wq[(0 * 16 + tb + 1) * 64 + ln];
  #pragma unroll
  for (int s = 0; s < 8; ++s) {
    short8 bn0, bn1;
    if (s < 7) {
      bn0 = Wq[((s + 1) * 16 + tb + 0) * 64 + ln];
      bn1 = Wq[((s + 1) * 16 + tb + 1) * 64 + ln];
    }
    short8 af[4];
    #pragma unroll
    for (int mt = 0; mt < 4; ++mt)
      af[mt] = *(const short8*)(&Abf[(mt * 16 + c15) * AST + s * 32 + q * 8]);
    #pragma unroll
    for (int mt = 0; mt < 4; ++mt)
      acc[mt][0] = __builtin_amdgcn_mfma_f32_16x16x32_bf16(af[mt], bc0, acc[mt][0], 0, 0, 0);
    #pragma unroll
    for (int mt = 0; mt < 4; ++mt)
      acc[mt][1] = __builtin_amdgcn_mfma_f32_16x16x32_bf16(af[mt], bc1, acc[mt][1], 0, 0, 0);
    bc0 = bn0; bc1 = bn1;
  }

  // ---- phase 2: h = gelu(z + y*W1_last + b1); partial logits = h.W2 ----
  #pragma unroll
  for (int mt = 0; mt < 4; ++mt) {
    #pragma unroll
    for (int r = 0; r < 4; ++r) {
      int m = mt * 16 + q * 4 + r;    // D row = quad*4 + reg
      float ym = ynl[m];
      float p = 0.f;
      #pragma unroll
      for (int nt = 0; nt < 2; ++nt) {
        float z = acc[mt][nt][r] + ym * wlv[nt] + b1v[nt];
        p += fast_gelu(z) * w2v[nt];
      }
      p += __shfl_xor(p, 1);
      p += __shfl_xor(p, 2);
      p += __shfl_xor(p, 4);
      p += __shfl_xor(p, 8);
      if (c15 == 0) wlog[wv][m] = p;
    }
  }
  __syncthreads();

  if (wv >= 4) return;   // waves 4-7 done (no more barriers below)

  // ---- phase 3: masked softmax over Y=64, redundant in waves 0-3 ----
  float lg = b2s;
  #pragma unroll
  for (int w = 0; w < 8; ++w) lg += wlog[w][ln];
  float lm = (vv < 0.5f) ? -10000.0f : lg;
  float mx = lm;
  #pragma unroll
  for (int d = 32; d > 0; d >>= 1) mx = fmaxf(mx, __shfl_xor(mx, d));
  float e  = __expf(lm - mx) * vv;     // e*valid
  float s2 = e;
  #pragma unroll
  for (int d = 32; d > 0; d >>= 1) s2 += __shfl_xor(s2, d);
  float wgt = e / fmaxf(s2, 1e-6f);    // lane ln holds weight for y=ln

  // ---- phase 4: out[c] = sum_y A_bf16[y][c] * w[y]  (threads 0..255) ----
  float a0 = 0.f;
  #pragma unroll
  for (int y = 0; y < 64; ++y) {
    float wy = __shfl(wgt, y);         // literal lane -> v_readlane
    a0 = fmaf(bf2f(Abf[y * AST + tid]), wy, a0);
  }
  out[(size_t)tok * 256 + tid] = a0;
}

extern "C" void kernel_launch(void* const* d_in, const int* in_sizes, int n_in,
                              void* d_out, int out_size, void* d_ws, size_t ws_size,
                              hipStream_t stream) {
  const float* sampled = (const float*)d_in[0];
  const float* valid   = (const float*)d_in[1];
  const float* y_norm  = (const float*)d_in[2];
  const float* W1      = (const float*)d_in[3];   // [257,256]
  const float* b1      = (const float*)d_in[4];
  const float* W2      = (const float*)d_in[5];
  const float* b2      = (const float*)d_in[6];
  short* W1s = (short*)d_ws;                      // 128 KiB swizzled bf16 W1
  float* out = (float*)d_out;

  prep_w1<<<32, 256, 0, stream>>>(W1, W1s);
  agg_kernel<<<NTOK, 512, 0, stream>>>(sampled, valid, y_norm, W1, b1, W2, b2, W1s, out);
}